// Round 3
// baseline (156.297 us; speedup 1.0000x reference)
//
#include <hip/hip_runtime.h>

// Rowwise cosine similarity: out[r] = dot(a_r,b_r) * rsqrt(max(|a_r|^2,eps)) * rsqrt(max(|b_r|^2,eps))
// a, b: [16, 4096, 256] f32 contiguous -> 65536 rows of 256 floats.
//
// One THREAD per row (no cross-lane reduction at all). A 64-lane wave covers
// 64 consecutive rows = one contiguous 64 KB span. Each thread walks its row
// in 8 chunks of 8 float4 (128 B contiguous per array per chunk -> whole
// cache lines consumed inside one chunk; L1 handles the lane-interleaving).
// 16 float4 loads in flight per lane -> ~16 KB outstanding per wave, far
// above the ~9 KB/CU needed to cover HBM latency at the per-CU BW share.
// Store: lane i writes out[row i] -> perfectly coalesced.

#define D 256
#define EPS 1e-12f

__global__ __launch_bounds__(256) void cosine_tpr_kernel(
    const float* __restrict__ a,
    const float* __restrict__ b,
    float* __restrict__ out,
    int n_rows)
{
    const int row = blockIdx.x * 256 + threadIdx.x;
    if (row >= n_rows) return;

    const float4* a4 = reinterpret_cast<const float4*>(a + (size_t)row * D);
    const float4* b4 = reinterpret_cast<const float4*>(b + (size_t)row * D);

    float sa = 0.f, sb = 0.f, sab = 0.f;

    #pragma unroll
    for (int c = 0; c < 8; ++c) {
        float4 av[8], bv[8];
        #pragma unroll
        for (int j = 0; j < 8; ++j) av[j] = a4[c * 8 + j];
        #pragma unroll
        for (int j = 0; j < 8; ++j) bv[j] = b4[c * 8 + j];
        #pragma unroll
        for (int j = 0; j < 8; ++j) {
            sa  = fmaf(av[j].x, av[j].x, fmaf(av[j].y, av[j].y, fmaf(av[j].z, av[j].z, fmaf(av[j].w, av[j].w, sa))));
            sb  = fmaf(bv[j].x, bv[j].x, fmaf(bv[j].y, bv[j].y, fmaf(bv[j].z, bv[j].z, fmaf(bv[j].w, bv[j].w, sb))));
            sab = fmaf(av[j].x, bv[j].x, fmaf(av[j].y, bv[j].y, fmaf(av[j].z, bv[j].z, fmaf(av[j].w, bv[j].w, sab))));
        }
    }

    out[row] = sab * rsqrtf(fmaxf(sa, EPS)) * rsqrtf(fmaxf(sb, EPS));
}

extern "C" void kernel_launch(void* const* d_in, const int* in_sizes, int n_in,
                              void* d_out, int out_size, void* d_ws, size_t ws_size,
                              hipStream_t stream)
{
    const float* a = (const float*)d_in[0];
    const float* b = (const float*)d_in[1];
    float* out = (float*)d_out;

    const int n_rows = out_size;            // 16 * 4096 = 65536
    const int grid = (n_rows + 255) / 256;  // 256 blocks -> 4 waves/CU, long-lived

    cosine_tpr_kernel<<<grid, 256, 0, stream>>>(a, b, out, n_rows);
}

// Round 4
// 144.516 us; speedup vs baseline: 1.0815x; 1.0815x over previous
//
#include <hip/hip_runtime.h>

// Rowwise cosine similarity: out[r] = dot(a_r,b_r) * rsqrt(max(|a_r|^2,eps)) * rsqrt(max(|b_r|^2,eps))
// a, b: [16, 4096, 256] f32 -> 65536 rows of 256 floats.
//
// PERSISTENT wave-per-row: grid = 2048 blocks x 4 waves = 8192 waves, all
// resident (32 waves/CU). Each wave loops over 8 rows (grid-stride), with a
// one-row software pipeline: the next row's two float4 loads (vmcnt) are
// issued BEFORE the current row's 18-shuffle butterfly (lgkmcnt) -- separate
// wait counters, so the serial shuffle tail overlaps the next loads and the
// load pipe never drains between rows. Loads: lane i reads float4 i of the
// row -> 64 x 16 B = 1 KB contiguous per instruction, perfectly coalesced.

#define D 256
#define EPS 1e-12f

__global__ __launch_bounds__(256, 8) void cosine_pers_kernel(
    const float* __restrict__ a,
    const float* __restrict__ b,
    float* __restrict__ out,
    int n_rows)
{
    const int lane   = threadIdx.x & 63;
    const int gwave  = blockIdx.x * 4 + (threadIdx.x >> 6);
    const int nwaves = gridDim.x * 4;

    const float4* __restrict__ a4 = reinterpret_cast<const float4*>(a);
    const float4* __restrict__ b4 = reinterpret_cast<const float4*>(b);

    int row = gwave;
    if (row >= n_rows) return;

    float4 av = a4[(size_t)row * 64 + lane];
    float4 bv = b4[(size_t)row * 64 + lane];

    for (;;) {
        const int  nrow = row + nwaves;   // wave-uniform -> no divergence
        const bool more = (nrow < n_rows);
        float4 av_n, bv_n;
        if (more) {
            av_n = a4[(size_t)nrow * 64 + lane];
            bv_n = b4[(size_t)nrow * 64 + lane];
        }

        float sa  = av.x*av.x + av.y*av.y + av.z*av.z + av.w*av.w;
        float sb  = bv.x*bv.x + bv.y*bv.y + bv.z*bv.z + bv.w*bv.w;
        float sab = av.x*bv.x + av.y*bv.y + av.z*bv.z + av.w*bv.w;

        #pragma unroll
        for (int off = 32; off > 0; off >>= 1) {
            sa  += __shfl_xor(sa,  off, 64);
            sb  += __shfl_xor(sb,  off, 64);
            sab += __shfl_xor(sab, off, 64);
        }

        if (lane == 0)
            out[row] = sab * rsqrtf(fmaxf(sa, EPS)) * rsqrtf(fmaxf(sb, EPS));

        if (!more) break;
        row = nrow;
        av = av_n;
        bv = bv_n;
    }
}

extern "C" void kernel_launch(void* const* d_in, const int* in_sizes, int n_in,
                              void* d_out, int out_size, void* d_ws, size_t ws_size,
                              hipStream_t stream)
{
    const float* a = (const float*)d_in[0];
    const float* b = (const float*)d_in[1];
    float* out = (float*)d_out;

    const int n_rows = out_size;            // 16 * 4096 = 65536
    int grid = 2048;                        // 8 blocks/CU * 256 CUs -> all waves resident
    const int max_grid = (n_rows + 3) / 4;  // never more waves than rows
    if (grid > max_grid) grid = max_grid;

    cosine_pers_kernel<<<grid, 256, 0, stream>>>(a, b, out, n_rows);
}